// Round 13
// baseline (81.053 us; speedup 1.0000x reference)
//
#include <hip/hip_runtime.h>

// Problem constants (fixed by setup_inputs): B=8, H=W=512, D=32, K=64
#define B_    8
#define N_    (512 * 512)
#define D_    32
#define K_    64
#define TPB   256
#define NWAVE (TPB / 64)
#define KROW  36                 // row stride (floats): 16B-aligned, rotates banks
#define TABW  (K_ * KROW)        // 2304 floats per wave-private table
#define REC   (K_ * D_ + K_)     // per-block partial record: 2048 sums + 64 counts
#define RECQ  (REC / 4)          // 528 float4 quads per record

// ---------------------------------------------------------------------------
// Stage 1: per-block partial segment sums — CLAIM-CELL duplicate resolution.
// r10's quantified failure (+30 VALU/iter -> +33us) shows stage1 is VALU-
// issue-sensitive; the old order/nsame arithmetic was ~40 of ~68 VALU/iter.
// New scheme: all 8 lanes of an element ds_write claim[lb]=egl (same-address
// write: one lane wins), volatile read-back; the winning ELEMENT does the
// plain b128 RMW; loser elements (~11%) use ds_add atomics issued AFTER the
// winner's write in program order (same-wave DS ops execute in issue order).
// Counts: one exact ds_atomic_add(cnt[lb], 1.0) from d4==0 lanes.
// Labels now load PER-LANE from global (8 lanes share an address, 32B/wave,
// coalesced), 2-deep prefetched alongside the embedding float4.
// Claim read-back uses a volatile LDS pointer to defeat store-forwarding.
// ---------------------------------------------------------------------------
#define PROC(LB, V, PBASE)                                                    \
  {                                                                           \
    const int    lbc = LB;                                                    \
    const float4 vc  = V;                                                     \
    const int    pb  = (PBASE);                                               \
    if (pb < iend) {      /* uniform branch */                                \
      LB = lab[bbase + pb + eg];                                              \
      V  = embv[(bbase + pb + eg) * 8 + d4];                                  \
    }                                                                         \
    claimv[lbc] = egl;                        /* ds_write: one lane wins */   \
    const int win = (claimv[lbc] == egl);     /* volatile read-back */        \
    if (d4 == 0) atomicAdd(&cnt[lbc], 1.0f);  /* exact fp32 count */          \
    const int a = lbc * KROW + d4 * 4;                                        \
    if (win) {                                                                \
      float4 cur = *reinterpret_cast<const float4*>(tab + a);                 \
      cur.x += vc.x; cur.y += vc.y; cur.z += vc.z; cur.w += vc.w;             \
      *reinterpret_cast<float4*>(tab + a) = cur;                              \
    } else {  /* rare; lands after the winner's write in issue order */       \
      atomicAdd(&tab[a + 0], vc.x);                                           \
      atomicAdd(&tab[a + 1], vc.y);                                           \
      atomicAdd(&tab[a + 2], vc.z);                                           \
      atomicAdd(&tab[a + 3], vc.w);                                           \
    }                                                                         \
  }

__global__ __launch_bounds__(TPB) void seg_partial_kernel(
    const float* __restrict__ emb, const int* __restrict__ lab,
    float* __restrict__ partials, int blk_per_b)
{
    __shared__ __align__(16) float s_tab[NWAVE * TABW];
    __shared__ float s_cnt[NWAVE * K_];
    __shared__ int   s_claim[NWAVE * K_];

    for (int i = threadIdx.x; i < NWAVE * TABW; i += TPB) s_tab[i] = 0.f;
    for (int i = threadIdx.x; i < NWAVE * K_;  i += TPB) s_cnt[i] = 0.f;
    __syncthreads();

    const int tid  = threadIdx.x;
    const int wave = tid >> 6;
    const int lane = tid & 63;
    const int egl  = lane >> 3;          // element slot within wave: 0..7
    const int d4   = lane & 7;           // float4 slice within element: 0..7
    const int eg   = wave * 8 + egl;     // element slot within block-iter: 0..31

    float* __restrict__ tab = s_tab + wave * TABW;
    float* __restrict__ cnt = s_cnt + wave * K_;
    volatile int* claimv = s_claim + wave * K_;

    const int blk = blockIdx.x;
    const int b   = blk / blk_per_b;
    const int bib = blk - b * blk_per_b;
    const long long bbase = (long long)b * N_;
    const float4* __restrict__ embv = reinterpret_cast<const float4*>(emb);
    const int CHUNK = N_ / blk_per_b;    // contiguous elements per block
    int ib = bib * CHUNK;
    const int iend = ib + CHUNK;

    // prologue: fill both pipeline stages (A @ ib, B @ ib+32)
    int lbA = lab[bbase + ib + eg];
    float4 vA = embv[(bbase + ib + eg) * 8 + d4];
    int lbB = 0;
    float4 vB = make_float4(0.f, 0.f, 0.f, 0.f);
    if (ib + 32 < iend) {
        lbB = lab[bbase + ib + 32 + eg];
        vB  = embv[(bbase + ib + 32 + eg) * 8 + d4];
    }

    for (;;) {
        PROC(lbA, vA, ib + 64);
        ib += 32;
        if (ib >= iend) break;
        PROC(lbB, vB, ib + 64);
        ib += 32;
        if (ib >= iend) break;
    }
    __syncthreads();

    // merge the 4 wave tables, write one partial record per block
    float* out = partials + (size_t)blk * REC;
    for (int i = tid; i < K_ * D_; i += TPB) {
        int k = i >> 5, d = i & 31;
        float s = 0.f;
#pragma unroll
        for (int w = 0; w < NWAVE; ++w) s += s_tab[w * TABW + k * KROW + d];
        out[i] = s;
    }
    if (tid < K_) {
        float c = 0.f;
#pragma unroll
        for (int w = 0; w < NWAVE; ++w) c += s_cnt[w * K_ + tid];
        out[K_ * D_ + tid] = c;
    }
}

// ---------------------------------------------------------------------------
// Stage 2a: two-level reduction, level 1 (r9-proven).
// ---------------------------------------------------------------------------
__global__ __launch_bounds__(TPB) void seg_reduce_a(
    const float* __restrict__ partials, float* __restrict__ part2,
    int rpc, int nch)
{
    const int blk = blockIdx.x;
    const int b   = blk / nch;
    const int ch  = blk - b * nch;
    const int tid = threadIdx.x;

    const float4* __restrict__ p4 = reinterpret_cast<const float4*>(partials)
        + (size_t)((b * nch + ch) * rpc) * RECQ;
    float4* __restrict__ o4 = reinterpret_cast<float4*>(part2)
        + (size_t)blk * RECQ;

    float4 acc0 = make_float4(0.f, 0.f, 0.f, 0.f);
    float4 acc1 = acc0, acc2 = acc0;
#pragma unroll 4
    for (int r = 0; r < rpc; ++r) {
        const float4* rp = p4 + (size_t)r * RECQ;
        float4 v0 = rp[tid];
        float4 v1 = rp[tid + 256];
        acc0.x += v0.x; acc0.y += v0.y; acc0.z += v0.z; acc0.w += v0.w;
        acc1.x += v1.x; acc1.y += v1.y; acc1.z += v1.z; acc1.w += v1.w;
        if (tid < 16) {
            float4 v2 = rp[tid + 512];
            acc2.x += v2.x; acc2.y += v2.y; acc2.z += v2.z; acc2.w += v2.w;
        }
    }
    o4[tid]       = acc0;
    o4[tid + 256] = acc1;
    if (tid < 16) o4[tid + 512] = acc2;
}

// ---------------------------------------------------------------------------
// Stage 2b+3: one block per batch (r9-proven).
// ---------------------------------------------------------------------------
__global__ __launch_bounds__(TPB) void loss8_kernel(
    const float* __restrict__ part2, float* __restrict__ batch_loss,
    int nch)
{
    __shared__ __align__(16) float4 s_cent4[8 * K_];  // [j][k]
    __shared__ float s_cntsh[K_];
    __shared__ float s_pres[K_];
    __shared__ float s_wred[NWAVE];

    const int b   = blockIdx.x;
    const int tid = threadIdx.x;
    const float4* __restrict__ p4 = reinterpret_cast<const float4*>(part2)
        + (size_t)(b * nch) * RECQ;

    float4 acc0 = make_float4(0.f, 0.f, 0.f, 0.f);
    float4 acc1 = acc0, acc2 = acc0;
#pragma unroll 8
    for (int c = 0; c < nch; ++c) {
        const float4* rp = p4 + (size_t)c * RECQ;
        float4 v0 = rp[tid];
        float4 v1 = rp[tid + 256];
        acc0.x += v0.x; acc0.y += v0.y; acc0.z += v0.z; acc0.w += v0.w;
        acc1.x += v1.x; acc1.y += v1.y; acc1.z += v1.z; acc1.w += v1.w;
        if (tid < 16) {
            float4 v2 = rp[tid + 512];
            acc2.x += v2.x; acc2.y += v2.y; acc2.z += v2.z; acc2.w += v2.w;
        }
    }

    // scatter: quad q (<512) -> s_cent4[(q&7)*64 + (q>>3)]
    s_cent4[(tid & 7) * K_ + (tid >> 3)] = acc0;
    {
        const int q1 = tid + 256;
        s_cent4[(q1 & 7) * K_ + (q1 >> 3)] = acc1;
    }
    if (tid < 16) reinterpret_cast<float4*>(s_cntsh)[tid] = acc2;
    __syncthreads();

    if (tid < K_) s_pres[tid] = (s_cntsh[tid] > 0.5f) ? 1.f : 0.f;
    for (int i = tid; i < 8 * K_; i += TPB) {
        float inv = 1.0f / fmaxf(s_cntsh[i & 63], 1.0f);
        float4 c = s_cent4[i];
        c.x *= inv; c.y *= inv; c.z *= inv; c.w *= inv;
        s_cent4[i] = c;
    }
    __syncthreads();

    const int wave = tid >> 6, lane = tid & 63;

    float4 cb[8];
#pragma unroll
    for (int j = 0; j < 8; ++j) cb[j] = s_cent4[j * K_ + lane];
    const float pres2 = s_pres[lane];

    float acc = 0.f;
#pragma unroll 4
    for (int t = 0; t < 16; ++t) {
        const int k1 = wave * 16 + t;
        float dist = 0.f;
#pragma unroll
        for (int j = 0; j < 8; ++j) {
            float4 a = s_cent4[j * K_ + k1];   // wave-uniform broadcast
            dist += fabsf(a.x - cb[j].x) + fabsf(a.y - cb[j].y)
                  + fabsf(a.z - cb[j].z) + fabsf(a.w - cb[j].w);
        }
        float h = fmaxf(0.25f - dist, 0.f);
        float valid = (k1 < lane) ? s_pres[k1] * pres2 : 0.f;
        acc += valid * h * h;
    }
#pragma unroll
    for (int m = 32; m > 0; m >>= 1) acc += __shfl_xor(acc, m);
    if (lane == 0) s_wred[wave] = acc;
    __syncthreads();
    if (tid == 0) {
        float s = s_wred[0] + s_wred[1] + s_wred[2] + s_wred[3];
        float n = 0.f;
        for (int k = 0; k < K_; ++k) n += s_pres[k];
        float ncomp = n * (n - 1.f) * 0.5f;
        batch_loss[b] = (ncomp > 0.f) ? (s / ncomp) : 0.f;
    }
}

// ---------------------------------------------------------------------------
// Stage 4: average the 8 per-batch losses into out[0].
// ---------------------------------------------------------------------------
__global__ void final_kernel(const float* __restrict__ batch_loss,
                             float* __restrict__ out)
{
    if (threadIdx.x == 0) {
        float t = 0.f;
#pragma unroll
        for (int b = 0; b < B_; ++b) t += batch_loss[b];
        out[0] = t * (1.0f / (float)B_);
    }
}

// ---------------------------------------------------------------------------
extern "C" void kernel_launch(void* const* d_in, const int* in_sizes, int n_in,
                              void* d_out, int out_size, void* d_ws, size_t ws_size,
                              hipStream_t stream)
{
    const float* emb = (const float*)d_in[0];
    const int*   lab = (const int*)d_in[1];
    float*       out = (float*)d_out;
    float*       ws  = (float*)d_ws;

    int blk_per_b = 128;
    while (blk_per_b > 8) {
        size_t need = ((size_t)(blk_per_b * B_) * REC          // partials
                       + (size_t)(B_ * 8) * REC                // part2 (max)
                       + B_) * sizeof(float);
        if (need <= ws_size) break;
        blk_per_b >>= 1;
    }
    const int nblk = blk_per_b * B_;
    const int nch  = (blk_per_b >= 8) ? 8 : blk_per_b;
    const int rpc  = blk_per_b / nch;

    float* partials   = ws;
    float* part2      = ws + (size_t)nblk * REC;
    float* batch_loss = part2 + (size_t)(B_ * nch) * REC;

    seg_partial_kernel<<<nblk, TPB, 0, stream>>>(emb, lab, partials, blk_per_b);

    seg_reduce_a<<<B_ * nch, TPB, 0, stream>>>(partials, part2, rpc, nch);

    loss8_kernel<<<B_, TPB, 0, stream>>>(part2, batch_loss, nch);

    final_kernel<<<1, 64, 0, stream>>>(batch_loss, out);
}

// Round 14
// 79.374 us; speedup vs baseline: 1.0212x; 1.0212x over previous
//
#include <hip/hip_runtime.h>

// Problem constants (fixed by setup_inputs): B=8, H=W=512, D=32, K=64
#define B_    8
#define N_    (512 * 512)
#define D_    32
#define K_    64
#define TPB   256
#define NWAVE (TPB / 64)
#define KROW  36                 // row stride (floats): 16B-aligned, rotates banks
#define TABW  (K_ * KROW)        // 2304 floats per wave-private table
#define REC   (K_ * D_ + K_)     // per-block partial record: 2048 sums + 64 counts
#define RECQ  (REC / 4)          // 528 float4 quads per record

// ---------------------------------------------------------------------------
// Stage 1: per-block partial segment sums — SALU dup-resolution + read-ahead
// RMW pipeline. Labels are wave-uniform s_loads; duplicate analysis runs on
// the SCALAR pipe via a 64-bit occupancy bitmask (win bit = "no earlier
// element this iter has my label") and 8x8-bit packed labels. Lanes extract
// lb/win with v_bfe (3-4 VALU). The table ds_read for iteration i+1 is issued
// at the END of iteration i (after its write/atomics): same-wave DS ops
// execute in issue order, so read-after-write is safe even on address
// collision, and the ~120cy LDS read latency hides under a full iteration.
// Counts are no-return ds atomics (no stall; integer fp32 -> exact).
// Losers (win==0, ~4% of elements) use ds_add atomics issued AFTER the
// winner's write in program order. All registers NAMED (r4 scratch lesson).
// ---------------------------------------------------------------------------

// Pack current raw labels tn0..tn7 (SGPRs) -> per-lane LBN, WNN, AN.
#define PACKNEXT(LBN, WNN, AN)                                                \
  {                                                                           \
    unsigned long long occ = 1ull << tn0;                                     \
    unsigned wbits = 1u;                                                      \
    unsigned long long bt;                                                    \
    bt = 1ull << tn1; wbits |= ((occ & bt) ? 0u : 2u);   occ |= bt;           \
    bt = 1ull << tn2; wbits |= ((occ & bt) ? 0u : 4u);   occ |= bt;           \
    bt = 1ull << tn3; wbits |= ((occ & bt) ? 0u : 8u);   occ |= bt;           \
    bt = 1ull << tn4; wbits |= ((occ & bt) ? 0u : 16u);  occ |= bt;           \
    bt = 1ull << tn5; wbits |= ((occ & bt) ? 0u : 32u);  occ |= bt;           \
    bt = 1ull << tn6; wbits |= ((occ & bt) ? 0u : 64u);  occ |= bt;           \
    bt = 1ull << tn7; wbits |= ((occ & bt) ? 0u : 128u);                      \
    const unsigned plo = (unsigned)tn0 | ((unsigned)tn1 << 8) |               \
                         ((unsigned)tn2 << 16) | ((unsigned)tn3 << 24);       \
    const unsigned phi = (unsigned)tn4 | ((unsigned)tn5 << 8) |               \
                         ((unsigned)tn6 << 16) | ((unsigned)tn7 << 24);       \
    const unsigned lbsel = lohalf ? plo : phi;                                \
    LBN = (int)((lbsel >> sh8) & 63u);                                        \
    WNN = (int)((wbits >> egl) & 1u);                                         \
    AN  = LBN * KROW + d4x4;                                                  \
  }

// Process iter with set {AA,RR,VV,LBX,WNX}; prepare set {AN,RN,LBN,WNN};
// VV doubles as the 2-deep value-load target; LOADOK guards the +2 loads.
#define BODY(AA, RR, VV, LBX, WNX, AN, RN, LBN, WNN, LOADOK)                  \
  {                                                                           \
    if (WNX) {                                                                \
      float4 cur;                                                             \
      cur.x = RR.x + VV.x; cur.y = RR.y + VV.y;                               \
      cur.z = RR.z + VV.z; cur.w = RR.w + VV.w;                               \
      *reinterpret_cast<float4*>(tab + AA) = cur;                             \
    } else {  /* rare; lands after the winner's write in issue order */       \
      atomicAdd(&tab[AA + 0], VV.x);                                          \
      atomicAdd(&tab[AA + 1], VV.y);                                          \
      atomicAdd(&tab[AA + 2], VV.z);                                          \
      atomicAdd(&tab[AA + 3], VV.w);                                          \
    }                                                                         \
    if (d4 == 0) atomicAdd(&cnt[LBX], 1.0f);   /* no-return, no stall */      \
    PACKNEXT(LBN, WNN, AN);                    /* labels i+1 (SALU) */        \
    if (LOADOK) {                              /* uniform guard: +2 loads */  \
      tn0 = lpU[0]; tn1 = lpU[1]; tn2 = lpU[2]; tn3 = lpU[3];                 \
      tn4 = lpU[4]; tn5 = lpU[5]; tn6 = lpU[6]; tn7 = lpU[7];                 \
      VV  = pe[0];                                                            \
    }                                                                         \
    lpU += 32; pe += 256;                                                     \
    RN = *reinterpret_cast<const float4*>(tab + AN);  /* read-ahead */        \
  }

__global__ __launch_bounds__(TPB) void seg_partial_kernel(
    const float* __restrict__ emb, const int* __restrict__ lab,
    float* __restrict__ partials, int blk_per_b)
{
    __shared__ __align__(16) float s_tab[NWAVE * TABW];
    __shared__ float s_cnt[NWAVE * K_];

    for (int i = threadIdx.x; i < NWAVE * TABW; i += TPB) s_tab[i] = 0.f;
    for (int i = threadIdx.x; i < NWAVE * K_;  i += TPB) s_cnt[i] = 0.f;
    __syncthreads();

    const int tid  = threadIdx.x;
    const int wave = tid >> 6;
    const int lane = tid & 63;
    const int egl  = lane >> 3;           // element slot within wave: 0..7
    const int d4   = lane & 7;            // float4 slice within element: 0..7
    const int eg   = wave * 8 + egl;      // element slot within block-iter
    const int  d4x4   = d4 * 4;           // loop-invariant
    const int  sh8    = (egl & 3) * 8;    // loop-invariant
    const bool lohalf = (egl < 4);        // loop-invariant

    float* __restrict__ tab = s_tab + wave * TABW;
    float* __restrict__ cnt = s_cnt + wave * K_;

    const int blk = blockIdx.x;
    const int b   = blk / blk_per_b;
    const int bib = blk - b * blk_per_b;
    const long long bbase = (long long)b * N_;
    const float4* __restrict__ embv = reinterpret_cast<const float4*>(emb);
    const int CHUNK = N_ / blk_per_b;     // contiguous elements per block
    const int NIT   = CHUNK / 32;         // iterations (even for pow2 sizes)
    const int cstart = bib * CHUNK;
    const int wb = __builtin_amdgcn_readfirstlane(wave * 8);

    // uniform label pointer (s_load) and per-lane value pointer
    const int*    lpU = lab + bbase + cstart + wb;
    const float4* pe  = embv + (bbase + cstart + eg) * 8 + d4;

    // ---- prologue -------------------------------------------------------
    int tn0, tn1, tn2, tn3, tn4, tn5, tn6, tn7;
    tn0 = lpU[0]; tn1 = lpU[1]; tn2 = lpU[2]; tn3 = lpU[3];
    tn4 = lpU[4]; tn5 = lpU[5]; tn6 = lpU[6]; tn7 = lpU[7];

    int lbA, wnA, aA, lbB, wnB, aB;
    PACKNEXT(lbA, wnA, aA);               // labels_0 -> set A

    float4 vA = pe[0];                    // value iter0
    float4 vB = pe[256];                  // value iter1

    // raw labels_1 into tn
    tn0 = lpU[32]; tn1 = lpU[33]; tn2 = lpU[34]; tn3 = lpU[35];
    tn4 = lpU[36]; tn5 = lpU[37]; tn6 = lpU[38]; tn7 = lpU[39];

    lpU += 64;                            // -> labels_2
    pe  += 512;                           // -> value iter2

    float4 rA = *reinterpret_cast<const float4*>(tab + aA);  // read-ahead 0
    float4 rB = make_float4(0.f, 0.f, 0.f, 0.f);

    // ---- main loop (unroll 2; body i prepares i+1, loads i+2) -----------
    for (int it = 0; it < NIT; it += 2) {
        BODY(aA, rA, vA, lbA, wnA, aB, rB, lbB, wnB, (it + 2 < NIT));
        BODY(aB, rB, vB, lbB, wnB, aA, rA, lbA, wnA, (it + 3 < NIT));
    }
    __syncthreads();

    // merge the 4 wave tables, write one partial record per block
    float* out = partials + (size_t)blk * REC;
    for (int i = tid; i < K_ * D_; i += TPB) {
        int k = i >> 5, d = i & 31;
        float s = 0.f;
#pragma unroll
        for (int w = 0; w < NWAVE; ++w) s += s_tab[w * TABW + k * KROW + d];
        out[i] = s;
    }
    if (tid < K_) {
        float c = 0.f;
#pragma unroll
        for (int w = 0; w < NWAVE; ++w) c += s_cnt[w * K_ + tid];
        out[K_ * D_ + tid] = c;
    }
}

// ---------------------------------------------------------------------------
// Stage 2a: two-level reduction, level 1 (r9-proven).
// ---------------------------------------------------------------------------
__global__ __launch_bounds__(TPB) void seg_reduce_a(
    const float* __restrict__ partials, float* __restrict__ part2,
    int rpc, int nch)
{
    const int blk = blockIdx.x;
    const int b   = blk / nch;
    const int ch  = blk - b * nch;
    const int tid = threadIdx.x;

    const float4* __restrict__ p4 = reinterpret_cast<const float4*>(partials)
        + (size_t)((b * nch + ch) * rpc) * RECQ;
    float4* __restrict__ o4 = reinterpret_cast<float4*>(part2)
        + (size_t)blk * RECQ;

    float4 acc0 = make_float4(0.f, 0.f, 0.f, 0.f);
    float4 acc1 = acc0, acc2 = acc0;
#pragma unroll 4
    for (int r = 0; r < rpc; ++r) {
        const float4* rp = p4 + (size_t)r * RECQ;
        float4 v0 = rp[tid];
        float4 v1 = rp[tid + 256];
        acc0.x += v0.x; acc0.y += v0.y; acc0.z += v0.z; acc0.w += v0.w;
        acc1.x += v1.x; acc1.y += v1.y; acc1.z += v1.z; acc1.w += v1.w;
        if (tid < 16) {
            float4 v2 = rp[tid + 512];
            acc2.x += v2.x; acc2.y += v2.y; acc2.z += v2.z; acc2.w += v2.w;
        }
    }
    o4[tid]       = acc0;
    o4[tid + 256] = acc1;
    if (tid < 16) o4[tid + 512] = acc2;
}

// ---------------------------------------------------------------------------
// Stage 2b+3: one block per batch (r9-proven).
// ---------------------------------------------------------------------------
__global__ __launch_bounds__(TPB) void loss8_kernel(
    const float* __restrict__ part2, float* __restrict__ batch_loss,
    int nch)
{
    __shared__ __align__(16) float4 s_cent4[8 * K_];  // [j][k]
    __shared__ float s_cntsh[K_];
    __shared__ float s_pres[K_];
    __shared__ float s_wred[NWAVE];

    const int b   = blockIdx.x;
    const int tid = threadIdx.x;
    const float4* __restrict__ p4 = reinterpret_cast<const float4*>(part2)
        + (size_t)(b * nch) * RECQ;

    float4 acc0 = make_float4(0.f, 0.f, 0.f, 0.f);
    float4 acc1 = acc0, acc2 = acc0;
#pragma unroll 8
    for (int c = 0; c < nch; ++c) {
        const float4* rp = p4 + (size_t)c * RECQ;
        float4 v0 = rp[tid];
        float4 v1 = rp[tid + 256];
        acc0.x += v0.x; acc0.y += v0.y; acc0.z += v0.z; acc0.w += v0.w;
        acc1.x += v1.x; acc1.y += v1.y; acc1.z += v1.z; acc1.w += v1.w;
        if (tid < 16) {
            float4 v2 = rp[tid + 512];
            acc2.x += v2.x; acc2.y += v2.y; acc2.z += v2.z; acc2.w += v2.w;
        }
    }

    // scatter: quad q (<512) -> s_cent4[(q&7)*64 + (q>>3)]
    s_cent4[(tid & 7) * K_ + (tid >> 3)] = acc0;
    {
        const int q1 = tid + 256;
        s_cent4[(q1 & 7) * K_ + (q1 >> 3)] = acc1;
    }
    if (tid < 16) reinterpret_cast<float4*>(s_cntsh)[tid] = acc2;
    __syncthreads();

    if (tid < K_) s_pres[tid] = (s_cntsh[tid] > 0.5f) ? 1.f : 0.f;
    for (int i = tid; i < 8 * K_; i += TPB) {
        float inv = 1.0f / fmaxf(s_cntsh[i & 63], 1.0f);
        float4 c = s_cent4[i];
        c.x *= inv; c.y *= inv; c.z *= inv; c.w *= inv;
        s_cent4[i] = c;
    }
    __syncthreads();

    const int wave = tid >> 6, lane = tid & 63;

    float4 cb[8];
#pragma unroll
    for (int j = 0; j < 8; ++j) cb[j] = s_cent4[j * K_ + lane];
    const float pres2 = s_pres[lane];

    float acc = 0.f;
#pragma unroll 4
    for (int t = 0; t < 16; ++t) {
        const int k1 = wave * 16 + t;
        float dist = 0.f;
#pragma unroll
        for (int j = 0; j < 8; ++j) {
            float4 a = s_cent4[j * K_ + k1];   // wave-uniform broadcast
            dist += fabsf(a.x - cb[j].x) + fabsf(a.y - cb[j].y)
                  + fabsf(a.z - cb[j].z) + fabsf(a.w - cb[j].w);
        }
        float h = fmaxf(0.25f - dist, 0.f);
        float valid = (k1 < lane) ? s_pres[k1] * pres2 : 0.f;
        acc += valid * h * h;
    }
#pragma unroll
    for (int m = 32; m > 0; m >>= 1) acc += __shfl_xor(acc, m);
    if (lane == 0) s_wred[wave] = acc;
    __syncthreads();
    if (tid == 0) {
        float s = s_wred[0] + s_wred[1] + s_wred[2] + s_wred[3];
        float n = 0.f;
        for (int k = 0; k < K_; ++k) n += s_pres[k];
        float ncomp = n * (n - 1.f) * 0.5f;
        batch_loss[b] = (ncomp > 0.f) ? (s / ncomp) : 0.f;
    }
}

// ---------------------------------------------------------------------------
// Stage 4: average the 8 per-batch losses into out[0].
// ---------------------------------------------------------------------------
__global__ void final_kernel(const float* __restrict__ batch_loss,
                             float* __restrict__ out)
{
    if (threadIdx.x == 0) {
        float t = 0.f;
#pragma unroll
        for (int b = 0; b < B_; ++b) t += batch_loss[b];
        out[0] = t * (1.0f / (float)B_);
    }
}

// ---------------------------------------------------------------------------
extern "C" void kernel_launch(void* const* d_in, const int* in_sizes, int n_in,
                              void* d_out, int out_size, void* d_ws, size_t ws_size,
                              hipStream_t stream)
{
    const float* emb = (const float*)d_in[0];
    const int*   lab = (const int*)d_in[1];
    float*       out = (float*)d_out;
    float*       ws  = (float*)d_ws;

    int blk_per_b = 128;
    while (blk_per_b > 8) {
        size_t need = ((size_t)(blk_per_b * B_) * REC          // partials
                       + (size_t)(B_ * 8) * REC                // part2 (max)
                       + B_) * sizeof(float);
        if (need <= ws_size) break;
        blk_per_b >>= 1;
    }
    const int nblk = blk_per_b * B_;
    const int nch  = (blk_per_b >= 8) ? 8 : blk_per_b;
    const int rpc  = blk_per_b / nch;

    float* partials   = ws;
    float* part2      = ws + (size_t)nblk * REC;
    float* batch_loss = part2 + (size_t)(B_ * nch) * REC;

    seg_partial_kernel<<<nblk, TPB, 0, stream>>>(emb, lab, partials, blk_per_b);

    seg_reduce_a<<<B_ * nch, TPB, 0, stream>>>(partials, part2, rpc, nch);

    loss8_kernel<<<B_, TPB, 0, stream>>>(part2, batch_loss, nch);

    final_kernel<<<1, 64, 0, stream>>>(batch_loss, out);
}